// Round 12
// baseline (1367.747 us; speedup 1.0000x reference)
//
#include <hip/hip_runtime.h>
#include <hip/hip_bf16.h>
#include <hip/hip_fp16.h>
#include <math.h>

#define Q_N 4096
#define M_N 65536
#define D_N 1024
#define TOPK 8
#define SEGS 32
#define KPS (M_N / SEGS)       // 2048 keys per segment
#define CANDS (SEGS * TOPK)    // 256 candidates per query
#define NRES 32                // rescored candidates per query

// MFMA tile params: 128q x 256k block, BK=64, 8 waves in 4k x 2q (wave=64k x 64q)
#define BMQ 128                // queries per block
#define BNK 256                // keys per tile-step
#define BK 64
#define NKT (D_N / BK)         // 16 K-tiles per subtile
#define NSUB (KPS / BNK)       // 8 subtiles per segment
#define NTT (NSUB * NKT)       // 128 K-tile steps per block
#define QT (Q_N / BMQ)         // 32 query tiles

typedef short s16x8 __attribute__((ext_vector_type(8)));
typedef float f32x4 __attribute__((ext_vector_type(4)));

__device__ __forceinline__ bool better(float v0, int i0, float v1, int i1) {
  return (v0 > v1) || (v0 == v1 && i0 < i1);
}

__device__ __forceinline__ unsigned short f2bf(float f) {
  union { __hip_bfloat16 h; unsigned short u; } c;
  c.h = __float2bfloat16(f);
  return c.u;
}

// async global->LDS, 16B per lane; lds base wave-uniform, dest linear (lane*16)
__device__ __forceinline__ void gll16(void* lds, const void* g) {
  __builtin_amdgcn_global_load_lds(
      (const __attribute__((address_space(1))) unsigned int*)(uintptr_t)g,
      (__attribute__((address_space(3))) unsigned int*)(uintptr_t)lds, 16, 0, 0);
}

// ---------------- K1: key norms + normalized bf16 conversion ----------------
__global__ __launch_bounds__(256) void knorm_scale_kernel(const float* __restrict__ keys,
                                                          unsigned short* __restrict__ kb,
                                                          float* __restrict__ rnk) {
  int row = blockIdx.x;
  int tid = threadIdx.x;
  float4 v = reinterpret_cast<const float4*>(keys + (size_t)row * D_N)[tid];
  float s = v.x * v.x + v.y * v.y + v.z * v.z + v.w * v.w;
#pragma unroll
  for (int off = 32; off > 0; off >>= 1) s += __shfl_down(s, off);
  __shared__ float part[4];
  __shared__ float rs;
  int lane = tid & 63, wid = tid >> 6;
  if (lane == 0) part[wid] = s;
  __syncthreads();
  if (tid == 0) {
    float t = part[0] + part[1] + part[2] + part[3];
    rs = 1.0f / fmaxf(sqrtf(t), 1e-12f);
  }
  __syncthreads();
  float r = rs;
  ushort4 o;
  o.x = f2bf(v.x * r); o.y = f2bf(v.y * r); o.z = f2bf(v.z * r); o.w = f2bf(v.w * r);
  reinterpret_cast<ushort4*>(kb + (size_t)row * D_N)[tid] = o;
  if (tid == 0) rnk[row] = r;
}

// ---------------- K2: query norms -> fp32 (rescore) + bf16 (MFMA) ----------
__global__ __launch_bounds__(256) void qnorm_dual_kernel(const float* __restrict__ q,
                                                         float* __restrict__ qn,
                                                         unsigned short* __restrict__ qb) {
  int row = blockIdx.x;
  int tid = threadIdx.x;
  float4 v = reinterpret_cast<const float4*>(q + (size_t)row * D_N)[tid];
  float s = v.x * v.x + v.y * v.y + v.z * v.z + v.w * v.w;
#pragma unroll
  for (int off = 32; off > 0; off >>= 1) s += __shfl_down(s, off);
  __shared__ float part[4];
  __shared__ float rs;
  int lane = tid & 63, wid = tid >> 6;
  if (lane == 0) part[wid] = s;
  __syncthreads();
  if (tid == 0) {
    float t = part[0] + part[1] + part[2] + part[3];
    rs = 1.0f / fmaxf(sqrtf(t), 1e-12f);
  }
  __syncthreads();
  float r = rs;
  float4 o;
  o.x = v.x * r; o.y = v.y * r; o.z = v.z * r; o.w = v.w * r;
  reinterpret_cast<float4*>(qn + (size_t)row * D_N)[tid] = o;
  ushort4 ob;
  ob.x = f2bf(o.x); ob.y = f2bf(o.y); ob.z = f2bf(o.z); ob.w = f2bf(o.w);
  reinterpret_cast<ushort4*>(qb + (size_t)row * D_N)[tid] = ob;
}

// ---------------- K3: bf16 MFMA sims + in-register per-segment top-8 --------
// 8-wave template-economics port: block = 128q x 2048k (one segment), per
// K-tile-step 256 keys x 64 K-dims staged; wave = 64k x 64q (acc 4x4 = 2.0
// MFMA per ds_read_b128). Ring-3 LDS (144KB, 1 block/CU), ONE raw barrier per
// K-tile, counted vmcnt(6); frag reads are plain C++ loads -> compiler
// interleaves reads with MFMA via partial lgkmcnt (no forced drain).
__global__ __launch_bounds__(512, 2) void simsb_kernel(const unsigned short* __restrict__ qb,
                                                       const unsigned short* __restrict__ kb,
                                                       float* __restrict__ cand_val,
                                                       int* __restrict__ cand_idx) {
  __shared__ __align__(16) union SmemU {
    struct {
      unsigned short A[3][BMQ * BK];  // 3 x 16 KB queries
      unsigned short B[3][BNK * BK];  // 3 x 32 KB keys
    } ab;                             // 144 KB
    struct {
      float v[BMQ * 16 * TOPK];       // 64 KB: per-query 16 lists (4 wr x 4 g)
      int i[BMQ * 16 * TOPK];         // 64 KB
    } mg;
  } smem;

  const int tid = threadIdx.x;
  const int lane = tid & 63;
  const int wid = tid >> 6;          // 0..7
  const int wr = wid >> 1;           // key quarter (0..3)
  const int wq = wid & 1;            // query half (0,1)

  // R11 cache-partitioned mapping: x = XCD, idx in-XCD (0..127)
  const int orig = blockIdx.x;
  const int x = orig & 7;
  const int idx = orig >> 3;
  const int qtile = ((x >> 1) << 3) + (idx & 7);
  const int seg = ((x & 1) << 4) + (idx >> 3);
  const int qbase = qtile * BMQ;
  const int segBase = seg * KPS;

  // staging geometry: 3-bit involutive chunk swizzle on global source (R9),
  // LDS dest linear. Row of 64 bf16 = 128 B = 8 chunks of 16 B.
  const int srow8 = lane >> 3;                         // row within 8-row group
  const int swzcol = (((lane & 7) ^ srow8) << 3);      // swizzled col (elems)
  // A: wave stages rows [wid*16,+16) (2 gll16); B: rows [wid*32,+32) (4 gll16)
  const unsigned short* aRow = qb + (size_t)(qbase + (wid << 4) + srow8) * D_N + swzcol;
  const unsigned short* bRow = kb + (size_t)(segBase + (wid << 5) + srow8) * D_N + swzcol;

  // fragment geometry (16x16x32, swapped operands): fr = lane&15, g = lane>>4
  const int fr = lane & 15;
  const int g = lane >> 4;
  int afOff[4][2], bqOff[4][2];
#pragma unroll
  for (int m = 0; m < 4; ++m)
#pragma unroll
    for (int kh = 0; kh < 2; ++kh) {
      const int phys = ((kh << 2) + g) ^ (fr & 7);
      afOff[m][kh] = ((wr << 6) + (m << 4) + fr) * 64 + (phys << 3);  // B buf (keys)
      bqOff[m][kh] = ((wq << 6) + (m << 4) + fr) * 64 + (phys << 3);  // A buf (queries)
    }

  // per-lane running top-8 for 4 queries (q = qbase + wq*64 + n*16 + fr)
  // over this lane's key partition (keys wr*64 + m*16 + g*4 + j)
  float lv[4][TOPK];
  int li[4][TOPK];
#pragma unroll
  for (int n = 0; n < 4; ++n)
#pragma unroll
    for (int j = 0; j < TOPK; ++j) { lv[n][j] = -1e30f; li[n][j] = 0x7fffffff; }

  f32x4 acc[4][4];   // [m key-frag][n query-frag]
#pragma unroll
  for (int m = 0; m < 4; ++m)
#pragma unroll
    for (int n = 0; n < 4; ++n) acc[m][n] = (f32x4)0.0f;

  // prologue: stage K-tiles 0,1 into ring slots 0,1 (6 gll16/wave each)
#pragma unroll
  for (int p = 0; p < 2; ++p) {
    const int kofs = p << 6;   // kt*64 (sub=0)
#pragma unroll
    for (int i = 0; i < 2; ++i)
      gll16(smem.ab.A[p] + (wid << 10) + (i << 9), aRow + kofs + (size_t)(i << 3) * D_N);
#pragma unroll
    for (int i = 0; i < 4; ++i)
      gll16(smem.ab.B[p] + (wid << 11) + (i << 9), bRow + kofs + (size_t)(i << 3) * D_N);
  }

  int cur = 0;
#pragma unroll 1
  for (int t = 0; t < NTT; ++t) {
    if (t < NTT - 1) {
      asm volatile("s_waitcnt vmcnt(6)" ::: "memory");   // own tile's 6 done
    } else {
      asm volatile("s_waitcnt vmcnt(0)" ::: "memory");
    }
    __builtin_amdgcn_sched_barrier(0);
    __builtin_amdgcn_s_barrier();   // single barrier per K-tile
    __builtin_amdgcn_sched_barrier(0);

    // restage tile t+2 into slot (cur+2)%3 = slot read at t-1 (readers done:
    // their MFMAs consumed the reads before they could reach this barrier)
    if (t + 2 < NTT) {
      const int t2 = t + 2;
      int nxt = cur + 2; if (nxt >= 3) nxt -= 3;
      const size_t aofs = ((t2 & 15) << 6);
      const size_t bofs = (size_t)(t2 >> 4) * (BNK * D_N) + ((t2 & 15) << 6);
#pragma unroll
      for (int i = 0; i < 2; ++i)
        gll16(smem.ab.A[nxt] + (wid << 10) + (i << 9), aRow + aofs + (size_t)(i << 3) * D_N);
#pragma unroll
      for (int i = 0; i < 4; ++i)
        gll16(smem.ab.B[nxt] + (wid << 11) + (i << 9), bRow + bofs + (size_t)(i << 3) * D_N);
    }

    // fragment reads (plain loads -> compiler pipelines into MFMA)
    const unsigned short* Ab = smem.ab.A[cur];
    const unsigned short* Bb = smem.ab.B[cur];
    s16x8 af[4][2], bq[4][2];
#pragma unroll
    for (int m = 0; m < 4; ++m)
#pragma unroll
      for (int kh = 0; kh < 2; ++kh) {
        af[m][kh] = *(const s16x8*)(Bb + afOff[m][kh]);
        bq[m][kh] = *(const s16x8*)(Ab + bqOff[m][kh]);
      }

    __builtin_amdgcn_s_setprio(1);
#pragma unroll
    for (int kh = 0; kh < 2; ++kh)
#pragma unroll
      for (int m = 0; m < 4; ++m)
#pragma unroll
        for (int n = 0; n < 4; ++n)
          acc[m][n] = __builtin_amdgcn_mfma_f32_16x16x32_bf16(af[m][kh], bq[n][kh], acc[m][n], 0, 0, 0);
    __builtin_amdgcn_s_setprio(0);

    // subtile boundary (every 16 K-tiles): fold acc into per-lane top-8, reset
    if ((t & (NKT - 1)) == NKT - 1) {
      const int kb0 = segBase + ((t >> 4) << 8) + (wr << 6) + (g << 2);
#pragma unroll
      for (int n = 0; n < 4; ++n)
#pragma unroll
        for (int m = 0; m < 4; ++m)
#pragma unroll
          for (int j = 0; j < 4; ++j) {
            float val = acc[m][n][j];
            acc[m][n][j] = 0.0f;
            int id = kb0 + (m << 4) + j;
            if (better(val, id, lv[n][TOPK - 1], li[n][TOPK - 1])) {
              float cv = val; int ci = id;
#pragma unroll
              for (int p = 0; p < TOPK; ++p) {
                if (better(cv, ci, lv[n][p], li[n][p])) {
                  float tv = lv[n][p]; int ti = li[n][p];
                  lv[n][p] = cv; li[n][p] = ci;
                  cv = tv; ci = ti;
                }
              }
            }
          }
    }

    ++cur; if (cur == 3) cur = 0;
  }

  __syncthreads();   // all LDS frag reads done before overlaying mg scratch

  // dump per-lane lists: query ql = wq*64 + n*16 + fr, list id = wr*4 + g
  {
    const int lid = (wr << 2) + g;
#pragma unroll
    for (int n = 0; n < 4; ++n) {
      const int ql = (wq << 6) + (n << 4) + fr;
#pragma unroll
      for (int j = 0; j < TOPK; ++j) {
        smem.mg.v[((ql << 4) + lid) * TOPK + j] = lv[n][j];
        smem.mg.i[((ql << 4) + lid) * TOPK + j] = li[n][j];
      }
    }
  }
  __syncthreads();

  // thread per query: 16-way merge of the 16 sorted lists -> top-8
  if (tid < BMQ) {
    const int rb = tid << 7;   // 16 lists x 8
    int pp[16];
#pragma unroll
    for (int l = 0; l < 16; ++l) pp[l] = 0;
    size_t base = (size_t)(qbase + tid) * CANDS + seg * TOPK;
#pragma unroll 1
    for (int j = 0; j < TOPK; ++j) {
      float bv = -1e38f; int bi = 0x7fffffff; int sel = 0;
#pragma unroll
      for (int l = 0; l < 16; ++l) {
        float tv = smem.mg.v[rb + l * 8 + pp[l]];
        int ti = smem.mg.i[rb + l * 8 + pp[l]];
        if (better(tv, ti, bv, bi)) { bv = tv; bi = ti; sel = l; }
      }
      cand_val[base + j] = bv;
      cand_idx[base + j] = bi;
#pragma unroll
      for (int l = 0; l < 16; ++l) pp[l] += (sel == l);
    }
  }
}

// ---------------- K4: merge + exact fp32 rescore + select + gather ---------
__global__ __launch_bounds__(256) void merge_kernel(const float* __restrict__ qn,
                                                    const float* __restrict__ keys,
                                                    const float* __restrict__ values,
                                                    const float* __restrict__ rnk,
                                                    const float* __restrict__ cand_val,
                                                    const int* __restrict__ cand_idx,
                                                    float* __restrict__ out) {
  const int q = blockIdx.x;
  const int tid = threadIdx.x;
  const int lane = tid & 63;
  const int w = tid >> 6;
  __shared__ float sv[CANDS];
  __shared__ int si[CANDS];
  sv[tid] = cand_val[(size_t)q * CANDS + tid];
  si[tid] = cand_idx[(size_t)q * CANDS + tid];
  __syncthreads();
  for (int k = 2; k <= CANDS; k <<= 1) {
    for (int j = k >> 1; j > 0; j >>= 1) {
      int ixj = tid ^ j;
      if (ixj > tid) {
        float v0 = sv[tid], v1 = sv[ixj];
        int i0 = si[tid], i1 = si[ixj];
        bool desc = ((tid & k) == 0);
        bool dosw = desc ? better(v1, i1, v0, i0) : better(v0, i0, v1, i1);
        if (dosw) { sv[tid] = v1; si[tid] = i1; sv[ixj] = v0; si[ixj] = i0; }
      }
      __syncthreads();
    }
  }
  __shared__ float rsc[NRES];
  const float* qrow = &qn[(size_t)q * D_N + lane * 16];
  float4 qv0 = *reinterpret_cast<const float4*>(qrow + 0);
  float4 qv1 = *reinterpret_cast<const float4*>(qrow + 4);
  float4 qv2 = *reinterpret_cast<const float4*>(qrow + 8);
  float4 qv3 = *reinterpret_cast<const float4*>(qrow + 12);
  for (int c = w; c < NRES; c += 4) {
    int id = si[c];
    const float* kr = &keys[(size_t)id * D_N + lane * 16];
    float4 k0 = *reinterpret_cast<const float4*>(kr + 0);
    float4 k1 = *reinterpret_cast<const float4*>(kr + 4);
    float4 k2 = *reinterpret_cast<const float4*>(kr + 8);
    float4 k3 = *reinterpret_cast<const float4*>(kr + 12);
    float s = qv0.x * k0.x + qv0.y * k0.y + qv0.z * k0.z + qv0.w * k0.w
            + qv1.x * k1.x + qv1.y * k1.y + qv1.z * k1.z + qv1.w * k1.w
            + qv2.x * k2.x + qv2.y * k2.y + qv2.z * k2.z + qv2.w * k2.w
            + qv3.x * k3.x + qv3.y * k3.y + qv3.z * k3.z + qv3.w * k3.w;
#pragma unroll
    for (int off = 32; off > 0; off >>= 1) s += __shfl_down(s, off);
    if (lane == 0) rsc[c] = s * rnk[id];
  }
  __syncthreads();
  __shared__ int sel[TOPK];
  if (tid == 0) {
    unsigned used = 0;
    for (int j = 0; j < TOPK; ++j) {
      int best = -1;
      for (int c = 0; c < NRES; ++c) {
        if ((used >> c) & 1u) continue;
        if (best < 0 || better(rsc[c], si[c], rsc[best], si[best])) best = c;
      }
      used |= 1u << best;
      sel[j] = si[best];
    }
  }
  __syncthreads();
#pragma unroll
  for (int j = 0; j < TOPK; ++j) {
    int row = sel[j];
    float4 v = *reinterpret_cast<const float4*>(&values[(size_t)row * D_N + tid * 4]);
    *reinterpret_cast<float4*>(&out[(size_t)q * (TOPK * D_N) + j * D_N + tid * 4]) = v;
  }
}

extern "C" void kernel_launch(void* const* d_in, const int* in_sizes, int n_in,
                              void* d_out, int out_size, void* d_ws, size_t ws_size,
                              hipStream_t stream) {
  const float* query  = (const float*)d_in[0];
  const float* keys   = (const float*)d_in[1];
  const float* values = (const float*)d_in[2];
  float* out = (float*)d_out;
  char* ws = (char*)d_ws;

  const size_t offQn  = 0;
  const size_t offQb  = offQn + (size_t)Q_N * D_N * 4;
  const size_t offKb  = offQb + (size_t)Q_N * D_N * 2;
  const size_t offRnk = offKb + (size_t)M_N * D_N * 2;
  const size_t offCv  = offRnk + (size_t)M_N * 4;
  const size_t offCi  = offCv + (size_t)Q_N * CANDS * 4;

  float* qn = (float*)(ws + offQn);
  unsigned short* qb = (unsigned short*)(ws + offQb);
  unsigned short* kb = (unsigned short*)(ws + offKb);
  float* rnk = (float*)(ws + offRnk);
  float* cand_val = (float*)(ws + offCv);
  int* cand_idx = (int*)(ws + offCi);

  hipLaunchKernelGGL(knorm_scale_kernel, dim3(M_N), dim3(256), 0, stream, keys, kb, rnk);
  hipLaunchKernelGGL(qnorm_dual_kernel, dim3(Q_N), dim3(256), 0, stream, query, qn, qb);
  hipLaunchKernelGGL(simsb_kernel, dim3(QT * SEGS), dim3(512), 0, stream,
                     qb, kb, cand_val, cand_idx);
  hipLaunchKernelGGL(merge_kernel, dim3(Q_N), dim3(256), 0, stream,
                     qn, keys, values, rnk, cand_val, cand_idx, out);
}